// Round 8
// baseline (479.511 us; speedup 1.0000x reference)
//
#include <hip/hip_runtime.h>
#include <hip/hip_fp16.h>
#include <math.h>

// Problem constants (P == D == 512).
static constexpr int PD = 512;
static constexpr float BASEV = 6.0f;
static constexpr int CAP = 320;   // slots per segment; counts ~150 +/- 12 => +14 sigma safe
static constexpr int HMAX = 4096; // rows mirrored into the f16 drug table

typedef float    f4v __attribute__((ext_vector_type(4)));
typedef int      i4v __attribute__((ext_vector_type(4)));
typedef int      i2v __attribute__((ext_vector_type(2)));
typedef _Float16 h4v __attribute__((ext_vector_type(4)));
typedef _Float16 h8v __attribute__((ext_vector_type(8)));

// ---------------------------------------------------------------------------
// Front kernel: three block ranges.
//   [0, CB)            : convert drug rows [0, NN) to an f16 mirror (halves
//                        accum's gather bytes; rows >= NN fall back to f32).
//   [CB, CB+AB)        : attention logits (const term once/block, 1 row/wave).
//   [CB+AB, ...)       : edge binning, O(1) searchsorted fast path.
// ---------------------------------------------------------------------------
__global__ __launch_bounds__(256) void front_kernel(
    const int* __restrict__ ei_f, const float* __restrict__ y_f,
    const int* __restrict__ ei_r, const float* __restrict__ y_r,
    const int* __restrict__ nb_f, const int* __restrict__ nb_r,
    const float* __restrict__ target, const float* __restrict__ formF,
    const float* __restrict__ roleF, const float* __restrict__ lemb,
    const float* __restrict__ W1, const float* __restrict__ b1,
    const float* __restrict__ W2, const float* __restrict__ b2,
    const float* __restrict__ drug, _Float16* __restrict__ drugh,
    int N, int E, int NN, int CB, int AB, int EBf,
    int* __restrict__ cnt, int2* __restrict__ bins,
    float* __restrict__ logits) {
    __shared__ float sred[384];
    int b = blockIdx.x;
    if (b < CB) {
        // ---- f32 -> f16 mirror of drug rows [0, NN) ----
        int i = (b * 256 + threadIdx.x) * 8;
        if (i < NN * PD) {
            float4 a = *(const float4*)(drug + i);
            float4 c = *(const float4*)(drug + i + 4);
            h8v hv;
            hv[0] = (_Float16)a.x; hv[1] = (_Float16)a.y;
            hv[2] = (_Float16)a.z; hv[3] = (_Float16)a.w;
            hv[4] = (_Float16)c.x; hv[5] = (_Float16)c.y;
            hv[6] = (_Float16)c.z; hv[7] = (_Float16)c.w;
            *reinterpret_cast<h8v*>(drugh + i) = hv;
        }
    } else if (b >= CB + AB) {
        // ---- edge binning: 1024 edges per block, 4 per thread ----
        int b2 = b - CB - AB;
        bool role = b2 >= EBf;
        const int* nb = role ? nb_r : nb_f;
        const int* ei = role ? ei_r : ei_f;
        const float* yy = role ? y_r : y_f;
        int base = (role ? b2 - EBf : b2) * 1024;
        int nb0 = nb[0];
#pragma unroll
        for (int r = 0; r < 4; r++) {
            int e = base + threadIdx.x + r * 256;
            if (e >= E) continue;
            int v = ei[e];
            int g = v - nb0; g = g < 0 ? 0 : (g >= N ? N - 1 : g);
            int pos;
            if (nb[g] == v && (g == 0 || nb[g - 1] < v)) {
                pos = g;                           // O(1) hit (shifted-identity table)
            } else {
                int lo = 0, hi = N;                // general fallback
                while (lo < hi) { int mid = (lo + hi) >> 1; if (nb[mid] < v) lo = mid + 1; else hi = mid; }
                pos = lo < N ? lo : N - 1;         // clip(ss, 0, N-1)
                if (nb[pos] != v) continue;        // invalid edge -> weight 0
            }
            int s = role ? N + pos : pos;
            float w = yy[e] - BASEV;
            int slot = atomicAdd(&cnt[s], 1);
            if (slot < CAP) {
                i2v val; val.x = ei[E + e]; val.y = __float_as_int(w);
                __builtin_nontemporal_store(val, reinterpret_cast<i2v*>(bins + (size_t)s * CAP + slot));
            }
        }
    } else {
        // ---- attention ----
        float* spart = sred;                 // [4][64]
        float* sc0 = spart + 256;            // [64]
        float* sc1 = spart + 320;            // [64]
        int jj = threadIdx.x & 63, ck = threadIdx.x >> 6;
        const float* Wc = W1 + jj;
        float tp = 0.f;
        int p0 = ck * 128;
        for (int p = p0; p < p0 + 128; p += 4) {
            float4 tv = *(const float4*)(target + p);
            tp += tv.x * Wc[(size_t)(p + 0) * 64] + tv.y * Wc[(size_t)(p + 1) * 64]
                + tv.z * Wc[(size_t)(p + 2) * 64] + tv.w * Wc[(size_t)(p + 3) * 64];
        }
        spart[ck * 64 + jj] = tp;
        __syncthreads();
        if (ck == 0) {
            float c = b1[jj] + spart[jj] + spart[64 + jj] + spart[128 + jj] + spart[192 + jj];
            float c0 = c, c1 = c;
            for (int q = 0; q < 16; q++) {
                float wq = Wc[(size_t)(2 * PD + q) * 64];
                c0 += lemb[q] * wq;
                c1 += lemb[16 + q] * wq;
            }
            sc0[jj] = c0; sc1[jj] = c1;
        }
        __syncthreads();
        int wave = threadIdx.x >> 6, lane = threadIdx.x & 63;
        int rr = (b - CB) * 4 + wave;
        int nseg = 2 * N;
        if (rr >= nseg) return;
        bool rl = rr >= N;
        const float* z = rl ? roleF + (size_t)(rr - N) * PD : formF + (size_t)rr * PD;
        const float* Wz = W1 + (size_t)PD * 64 + lane;
        float hA = rl ? sc1[lane] : sc0[lane];
        float hB = 0.f, hC = 0.f, hD = 0.f;
        for (int p = 0; p < PD; p += 8) {     // 4 independent FMA chains
            float4 z0 = *(const float4*)(z + p);
            float4 z1 = *(const float4*)(z + p + 4);
            hA += z0.x * Wz[(size_t)(p + 0) * 64] + z0.y * Wz[(size_t)(p + 1) * 64];
            hB += z0.z * Wz[(size_t)(p + 2) * 64] + z0.w * Wz[(size_t)(p + 3) * 64];
            hC += z1.x * Wz[(size_t)(p + 4) * 64] + z1.y * Wz[(size_t)(p + 5) * 64];
            hD += z1.z * Wz[(size_t)(p + 6) * 64] + z1.w * Wz[(size_t)(p + 7) * 64];
        }
        float hh = (hA + hB) + (hC + hD);
        hh = hh > 0.f ? hh : 0.2f * hh;       // LeakyReLU(0.2)
        float vv = hh * W2[lane];
#pragma unroll
        for (int off = 32; off > 0; off >>= 1) vv += __shfl_down(vv, off, 64);
        if (lane == 0) logits[rr] = vv + b2[0];
    }
}

// per-entry fallback row FMA (handles j outside the f16 mirror)
__device__ inline void rowfma(float4& acc, float w, int j, int t, int NN,
                              const float* __restrict__ drug,
                              const _Float16* __restrict__ drugh) {
    if (j < NN) {
        h4v hv = *(const h4v*)(drugh + (size_t)j * PD + 4 * t);
        acc.x += w * (float)hv[0]; acc.y += w * (float)hv[1];
        acc.z += w * (float)hv[2]; acc.w += w * (float)hv[3];
    } else {
        float4 d = ((const float4*)(drug + (size_t)j * PD))[t];
        acc.x += w * d.x; acc.y += w * d.y; acc.z += w * d.z; acc.w += w * d.w;
    }
}

// ---------------------------------------------------------------------------
// Accumulate sum_k w_k * drug[j_k] per segment. One block (128 thr) per
// segment; 16 independent row loads in flight; rows come from the f16 mirror
// (8 B/lane/row) -> HALF the gather bytes of f32. Uniform fast-path check per
// 16-batch (all j < NN); general f32 fallback otherwise.
// Extra block (b == nseg) computes global softmax stats (m, Z) into sm[].
// ---------------------------------------------------------------------------
__global__ __launch_bounds__(128) void accum_kernel(const int* __restrict__ cnt,
                                                    const int2* __restrict__ bins,
                                                    const float* __restrict__ drug,
                                                    const _Float16* __restrict__ drugh,
                                                    const float* __restrict__ logits,
                                                    int nseg, int NN,
                                                    float* __restrict__ sm,
                                                    float* __restrict__ msgs) {
    int b = blockIdx.x;
    int t = threadIdx.x;
    if (b == nseg) {
        __shared__ float red[128];
        float m = -1e30f;
        for (int s = t; s < nseg; s += 128) m = fmaxf(m, logits[s]);
        red[t] = m; __syncthreads();
        for (int o = 64; o > 0; o >>= 1) { if (t < o) red[t] = fmaxf(red[t], red[t + o]); __syncthreads(); }
        m = red[0]; __syncthreads();
        float sum = 0.f;
        for (int s = t; s < nseg; s += 128) sum += expf(logits[s] - m);
        red[t] = sum; __syncthreads();
        for (int o = 64; o > 0; o >>= 1) { if (t < o) red[t] += red[t + o]; __syncthreads(); }
        if (t == 0) { sm[0] = m; sm[1] = red[0]; }
        return;
    }
    int n = cnt[b]; n = n < CAP ? n : CAP;
    const int2* bb = bins + (size_t)b * CAP;
    float4 acc = make_float4(0.f, 0.f, 0.f, 0.f);
    const _Float16* dh = drugh + 4 * t;
    int k = 0;
    for (; k + 15 < n; k += 16) {
        i4v q0 = __builtin_nontemporal_load(reinterpret_cast<const i4v*>(bb + k + 0));
        i4v q1 = __builtin_nontemporal_load(reinterpret_cast<const i4v*>(bb + k + 2));
        i4v q2 = __builtin_nontemporal_load(reinterpret_cast<const i4v*>(bb + k + 4));
        i4v q3 = __builtin_nontemporal_load(reinterpret_cast<const i4v*>(bb + k + 6));
        i4v q4 = __builtin_nontemporal_load(reinterpret_cast<const i4v*>(bb + k + 8));
        i4v q5 = __builtin_nontemporal_load(reinterpret_cast<const i4v*>(bb + k + 10));
        i4v q6 = __builtin_nontemporal_load(reinterpret_cast<const i4v*>(bb + k + 12));
        i4v q7 = __builtin_nontemporal_load(reinterpret_cast<const i4v*>(bb + k + 14));
        int mx = max(max(max(max(q0.x, q0.z), max(q1.x, q1.z)),
                         max(max(q2.x, q2.z), max(q3.x, q3.z))),
                     max(max(max(q4.x, q4.z), max(q5.x, q5.z)),
                         max(max(q6.x, q6.z), max(q7.x, q7.z))));
        if (mx < NN) {                       // uniform across block (bb broadcast)
            h4v d0 = *(const h4v*)(dh + (size_t)q0.x * PD);
            h4v d1 = *(const h4v*)(dh + (size_t)q0.z * PD);
            h4v d2 = *(const h4v*)(dh + (size_t)q1.x * PD);
            h4v d3 = *(const h4v*)(dh + (size_t)q1.z * PD);
            h4v d4 = *(const h4v*)(dh + (size_t)q2.x * PD);
            h4v d5 = *(const h4v*)(dh + (size_t)q2.z * PD);
            h4v d6 = *(const h4v*)(dh + (size_t)q3.x * PD);
            h4v d7 = *(const h4v*)(dh + (size_t)q3.z * PD);
            h4v d8 = *(const h4v*)(dh + (size_t)q4.x * PD);
            h4v d9 = *(const h4v*)(dh + (size_t)q4.z * PD);
            h4v da = *(const h4v*)(dh + (size_t)q5.x * PD);
            h4v db = *(const h4v*)(dh + (size_t)q5.z * PD);
            h4v dc = *(const h4v*)(dh + (size_t)q6.x * PD);
            h4v dd = *(const h4v*)(dh + (size_t)q6.z * PD);
            h4v de = *(const h4v*)(dh + (size_t)q7.x * PD);
            h4v df = *(const h4v*)(dh + (size_t)q7.z * PD);
            float w0 = __int_as_float(q0.y), w1 = __int_as_float(q0.w);
            float w2 = __int_as_float(q1.y), w3 = __int_as_float(q1.w);
            float w4 = __int_as_float(q2.y), w5 = __int_as_float(q2.w);
            float w6 = __int_as_float(q3.y), w7 = __int_as_float(q3.w);
            float w8 = __int_as_float(q4.y), w9 = __int_as_float(q4.w);
            float wa = __int_as_float(q5.y), wb = __int_as_float(q5.w);
            float wc = __int_as_float(q6.y), wd = __int_as_float(q6.w);
            float we = __int_as_float(q7.y), wf = __int_as_float(q7.w);
            acc.x += w0 * (float)d0[0]; acc.y += w0 * (float)d0[1]; acc.z += w0 * (float)d0[2]; acc.w += w0 * (float)d0[3];
            acc.x += w1 * (float)d1[0]; acc.y += w1 * (float)d1[1]; acc.z += w1 * (float)d1[2]; acc.w += w1 * (float)d1[3];
            acc.x += w2 * (float)d2[0]; acc.y += w2 * (float)d2[1]; acc.z += w2 * (float)d2[2]; acc.w += w2 * (float)d2[3];
            acc.x += w3 * (float)d3[0]; acc.y += w3 * (float)d3[1]; acc.z += w3 * (float)d3[2]; acc.w += w3 * (float)d3[3];
            acc.x += w4 * (float)d4[0]; acc.y += w4 * (float)d4[1]; acc.z += w4 * (float)d4[2]; acc.w += w4 * (float)d4[3];
            acc.x += w5 * (float)d5[0]; acc.y += w5 * (float)d5[1]; acc.z += w5 * (float)d5[2]; acc.w += w5 * (float)d5[3];
            acc.x += w6 * (float)d6[0]; acc.y += w6 * (float)d6[1]; acc.z += w6 * (float)d6[2]; acc.w += w6 * (float)d6[3];
            acc.x += w7 * (float)d7[0]; acc.y += w7 * (float)d7[1]; acc.z += w7 * (float)d7[2]; acc.w += w7 * (float)d7[3];
            acc.x += w8 * (float)d8[0]; acc.y += w8 * (float)d8[1]; acc.z += w8 * (float)d8[2]; acc.w += w8 * (float)d8[3];
            acc.x += w9 * (float)d9[0]; acc.y += w9 * (float)d9[1]; acc.z += w9 * (float)d9[2]; acc.w += w9 * (float)d9[3];
            acc.x += wa * (float)da[0]; acc.y += wa * (float)da[1]; acc.z += wa * (float)da[2]; acc.w += wa * (float)da[3];
            acc.x += wb * (float)db[0]; acc.y += wb * (float)db[1]; acc.z += wb * (float)db[2]; acc.w += wb * (float)db[3];
            acc.x += wc * (float)dc[0]; acc.y += wc * (float)dc[1]; acc.z += wc * (float)dc[2]; acc.w += wc * (float)dc[3];
            acc.x += wd * (float)dd[0]; acc.y += wd * (float)dd[1]; acc.z += wd * (float)dd[2]; acc.w += wd * (float)dd[3];
            acc.x += we * (float)de[0]; acc.y += we * (float)de[1]; acc.z += we * (float)de[2]; acc.w += we * (float)de[3];
            acc.x += wf * (float)df[0]; acc.y += wf * (float)df[1]; acc.z += wf * (float)df[2]; acc.w += wf * (float)df[3];
        } else {
            rowfma(acc, __int_as_float(q0.y), q0.x, t, NN, drug, drugh);
            rowfma(acc, __int_as_float(q0.w), q0.z, t, NN, drug, drugh);
            rowfma(acc, __int_as_float(q1.y), q1.x, t, NN, drug, drugh);
            rowfma(acc, __int_as_float(q1.w), q1.z, t, NN, drug, drugh);
            rowfma(acc, __int_as_float(q2.y), q2.x, t, NN, drug, drugh);
            rowfma(acc, __int_as_float(q2.w), q2.z, t, NN, drug, drugh);
            rowfma(acc, __int_as_float(q3.y), q3.x, t, NN, drug, drugh);
            rowfma(acc, __int_as_float(q3.w), q3.z, t, NN, drug, drugh);
            rowfma(acc, __int_as_float(q4.y), q4.x, t, NN, drug, drugh);
            rowfma(acc, __int_as_float(q4.w), q4.z, t, NN, drug, drugh);
            rowfma(acc, __int_as_float(q5.y), q5.x, t, NN, drug, drugh);
            rowfma(acc, __int_as_float(q5.w), q5.z, t, NN, drug, drugh);
            rowfma(acc, __int_as_float(q6.y), q6.x, t, NN, drug, drugh);
            rowfma(acc, __int_as_float(q6.w), q6.z, t, NN, drug, drugh);
            rowfma(acc, __int_as_float(q7.y), q7.x, t, NN, drug, drugh);
            rowfma(acc, __int_as_float(q7.w), q7.z, t, NN, drug, drugh);
        }
    }
    for (; k < n; k++) {
        int2 e0 = bb[k];
        rowfma(acc, __int_as_float(e0.y), e0.x, t, NN, drug, drugh);
    }
    ((float4*)(msgs + (size_t)b * PD))[t] = acc;
}

// ---------------------------------------------------------------------------
// Weighted row sum -> v_prior, using precomputed softmax stats sm = {m, Z}.
// ---------------------------------------------------------------------------
__global__ __launch_bounds__(128) void vprior_kernel(const float* __restrict__ logits,
                                                     const float* __restrict__ msgs,
                                                     const float* __restrict__ sm,
                                                     int nseg, float* __restrict__ v_prior) {
    int t = threadIdx.x;
    float m = sm[0];
    float inv = 1.f / sm[1];
    float4 acc = make_float4(0.f, 0.f, 0.f, 0.f);
    for (int s = blockIdx.x; s < nseg; s += gridDim.x) {
        float w = expf(logits[s] - m) * inv;
        float4 d = ((const float4*)(msgs + (size_t)s * PD))[t];
        acc.x += w * d.x; acc.y += w * d.y; acc.z += w * d.z; acc.w += w * d.w;
    }
    atomicAdd(&v_prior[4 * t + 0], acc.x);
    atomicAdd(&v_prior[4 * t + 1], acc.y);
    atomicAdd(&v_prior[4 * t + 2], acc.z);
    atomicAdd(&v_prior[4 * t + 3], acc.w);
}

// ---------------------------------------------------------------------------
// Fused tail (ONE block, 256 thr): h = PReLU(v_prior@Wi1+bi1);
// v = h@Wi2+bi2; x = target+v; LayerNorm -> out. Replaces 3 dispatches.
// v_prior is from the PREVIOUS kernel -> kernel-boundary coherence, plain loads.
// ---------------------------------------------------------------------------
__global__ __launch_bounds__(256) void tail_kernel(const float* __restrict__ v_prior,
                                                   const float* __restrict__ Wi1,
                                                   const float* __restrict__ bi1,
                                                   const float* __restrict__ alpha_p,
                                                   const float* __restrict__ Wi2,
                                                   const float* __restrict__ bi2,
                                                   const float* __restrict__ target,
                                                   const float* __restrict__ gamma,
                                                   const float* __restrict__ beta,
                                                   float* __restrict__ out) {
    __shared__ float vp[512];
    __shared__ float hs[512];
    __shared__ float red[256];
    int t = threadIdx.x;
    vp[t] = v_prior[t]; vp[t + 256] = v_prior[t + 256];
    __syncthreads();
    // mv1: cols 2t, 2t+1
    float2 ha = make_float2(0.f, 0.f);
    for (int d = 0; d < PD; d++) {
        float vd = vp[d];
        float2 w = ((const float2*)(Wi1 + (size_t)d * PD))[t];
        ha.x += vd * w.x; ha.y += vd * w.y;
    }
    float al = alpha_p[0];
    float h0 = ha.x + bi1[2 * t];     h0 = h0 > 0.f ? h0 : al * h0;
    float h1 = ha.y + bi1[2 * t + 1]; h1 = h1 > 0.f ? h1 : al * h1;
    hs[2 * t] = h0; hs[2 * t + 1] = h1;
    __syncthreads();
    // mv2
    float2 va = make_float2(0.f, 0.f);
    for (int q = 0; q < PD; q++) {
        float hq = hs[q];
        float2 w = ((const float2*)(Wi2 + (size_t)q * PD))[t];
        va.x += hq * w.x; va.y += hq * w.y;
    }
    float x0 = target[2 * t] + va.x + bi2[2 * t];
    float x1 = target[2 * t + 1] + va.y + bi2[2 * t + 1];
    // LayerNorm over 512 (2 per thread)
    red[t] = x0 + x1; __syncthreads();
    for (int o = 128; o > 0; o >>= 1) { if (t < o) red[t] += red[t + o]; __syncthreads(); }
    float mu = red[0] * (1.f / 512.f);
    __syncthreads();
    float d0 = x0 - mu, d1 = x1 - mu;
    red[t] = d0 * d0 + d1 * d1; __syncthreads();
    for (int o = 128; o > 0; o >>= 1) { if (t < o) red[t] += red[t + o]; __syncthreads(); }
    float rinv = 1.f / sqrtf(red[0] * (1.f / 512.f) + 1e-5f);
    out[2 * t]     = d0 * rinv * gamma[2 * t]     + beta[2 * t];
    out[2 * t + 1] = d1 * rinv * gamma[2 * t + 1] + beta[2 * t + 1];
}

// ---------------------------------------------------------------------------
extern "C" void kernel_launch(void* const* d_in, const int* in_sizes, int n_in,
                              void* d_out, int out_size, void* d_ws, size_t ws_size,
                              hipStream_t stream) {
    const float* target = (const float*)d_in[0];
    const float* formF  = (const float*)d_in[1];
    const float* roleF  = (const float*)d_in[2];
    const int*   nb_f   = (const int*)d_in[3];
    const int*   nb_r   = (const int*)d_in[4];
    const int*   ei_f   = (const int*)d_in[5];   // (2,E) flat: row0 src, row1 drug
    const float* y_f    = (const float*)d_in[6];
    const int*   ei_r   = (const int*)d_in[7];
    const float* y_r    = (const float*)d_in[8];
    const float* drug   = (const float*)d_in[9];
    const float* lemb   = (const float*)d_in[10];
    const float* W1     = (const float*)d_in[11];
    const float* b1     = (const float*)d_in[12];
    const float* W2     = (const float*)d_in[13];
    const float* b2     = (const float*)d_in[14];
    const float* Wi1    = (const float*)d_in[15];
    const float* bi1    = (const float*)d_in[16];
    const float* alpha  = (const float*)d_in[17];
    const float* Wi2    = (const float*)d_in[18];
    const float* bi2    = (const float*)d_in[19];
    const float* gamma  = (const float*)d_in[20];
    const float* beta   = (const float*)d_in[21];

    int N = in_sizes[3];
    int E = in_sizes[5] / 2;
    int nseg = 2 * N;
    int NN = N < HMAX ? N : HMAX;

    // workspace layout (4-byte words)
    int* ws = (int*)d_ws;
    int*      cnt     = ws + 0;                  // 4096  (zeroed)
    float*    v_prior = (float*)(ws + 4096);     // 512   (zeroed)
    float*    logits  = (float*)(ws + 4608);     // 4096
    float*    smbuf   = (float*)(ws + 8704);     // 2
    _Float16* drugh   = (_Float16*)(ws + 8712);  // HMAX*512 halves = 1048576 words
    int2*     bins    = (int2*)(ws + 8712 + HMAX * PD / 2);  // 8B aligned

    float* out  = (float*)d_out;
    float* msgs = out + PD;   // [2N, 512] = form_msgs then role_msgs

    hipMemsetAsync(ws, 0, 4608 * sizeof(int), stream);  // cnt + v_prior

    int CB  = (NN * PD + 2047) / 2048;       // convert blocks: 256 thr x 8 elems
    int AB  = (nseg + 3) / 4;                // attention blocks: 4 waves x 1 row
    int EBf = (E + 1023) / 1024;             // edge blocks per layer (4 edges/thread)
    front_kernel<<<CB + AB + 2 * EBf, 256, 0, stream>>>(ei_f, y_f, ei_r, y_r, nb_f, nb_r,
                                                        target, formF, roleF, lemb,
                                                        W1, b1, W2, b2, drug, drugh,
                                                        N, E, NN, CB, AB, EBf,
                                                        cnt, bins, logits);
    accum_kernel<<<nseg + 1, 128, 0, stream>>>(cnt, bins, drug, drugh, logits, nseg, NN, smbuf, msgs);
    vprior_kernel<<<256, 128, 0, stream>>>(logits, msgs, smbuf, nseg, v_prior);
    tail_kernel<<<1, 256, 0, stream>>>(v_prior, Wi1, bi1, alpha, Wi2, bi2,
                                       target, gamma, beta, out);
}

// Round 9
// 476.010 us; speedup vs baseline: 1.0074x; 1.0074x over previous
//
#include <hip/hip_runtime.h>
#include <math.h>

// Problem constants (P == D == 512).
static constexpr int PD = 512;
static constexpr float BASEV = 6.0f;
static constexpr int CAP = 320;   // slots per segment; counts ~150 +/- 12 => +14 sigma safe

typedef float f4v __attribute__((ext_vector_type(4)));
typedef int   i4v __attribute__((ext_vector_type(4)));
typedef int   i2v __attribute__((ext_vector_type(2)));

// ---------------------------------------------------------------------------
// Edge binning only (accum depends on its bins -> must be a separate dispatch).
// O(1) searchsorted fast path for shifted-identity neighbor tables; binary
// search fallback keeps generality.
// ---------------------------------------------------------------------------
__global__ __launch_bounds__(256) void edge_kernel(
    const int* __restrict__ ei_f, const float* __restrict__ y_f,
    const int* __restrict__ ei_r, const float* __restrict__ y_r,
    const int* __restrict__ nb_f, const int* __restrict__ nb_r,
    int N, int E, int EBf,
    int* __restrict__ cnt, int2* __restrict__ bins) {
    int b = blockIdx.x;
    bool role = b >= EBf;
    const int* nb = role ? nb_r : nb_f;
    const int* ei = role ? ei_r : ei_f;
    const float* yy = role ? y_r : y_f;
    int base = (role ? b - EBf : b) * 1024;
    int nb0 = nb[0];
#pragma unroll
    for (int r = 0; r < 4; r++) {
        int e = base + threadIdx.x + r * 256;
        if (e >= E) continue;
        int v = ei[e];
        int g = v - nb0; g = g < 0 ? 0 : (g >= N ? N - 1 : g);
        int pos;
        if (nb[g] == v && (g == 0 || nb[g - 1] < v)) {
            pos = g;                           // O(1) hit (shifted-identity table)
        } else {
            int lo = 0, hi = N;                // general fallback
            while (lo < hi) { int mid = (lo + hi) >> 1; if (nb[mid] < v) lo = mid + 1; else hi = mid; }
            pos = lo < N ? lo : N - 1;         // clip(ss, 0, N-1)
            if (nb[pos] != v) continue;        // invalid edge -> weight 0
        }
        int s = role ? N + pos : pos;
        float w = yy[e] - BASEV;
        int slot = atomicAdd(&cnt[s], 1);
        if (slot < CAP) {
            i2v val; val.x = ei[E + e]; val.y = __float_as_int(w);
            // NT: bins are streamed once downstream; keep them out of L2
            __builtin_nontemporal_store(val, reinterpret_cast<i2v*>(bins + (size_t)s * CAP + slot));
        }
    }
}

// ---------------------------------------------------------------------------
// Fused accum + attention (one dispatch, two block ranges):
//   b < nseg  : segment gather-accumulate (L2-latency-bound).
//   b >= nseg : attention logits, 2 rows per 128-thr block (FMA-bound).
// Co-residency overlaps the FMA waves with the gather waves; in R7 the
// attention ran serially inside the edge kernel instead.
// ---------------------------------------------------------------------------
__global__ __launch_bounds__(128) void accum_attn_kernel(
    const int* __restrict__ cnt, const int2* __restrict__ bins,
    const float* __restrict__ drug,
    const float* __restrict__ target, const float* __restrict__ formF,
    const float* __restrict__ roleF, const float* __restrict__ lemb,
    const float* __restrict__ W1, const float* __restrict__ b1,
    const float* __restrict__ W2, const float* __restrict__ b2,
    int nseg, float* __restrict__ logits, float* __restrict__ msgs) {
    __shared__ float sred[256];
    int b = blockIdx.x;
    int t = threadIdx.x;
    if (b >= nseg) {
        // ---- attention: const term once per block, then 1 row per wave ----
        int N = nseg >> 1;
        int a = b - nseg;
        float* spart = sred;                 // [2][64]
        float* sc0 = sred + 128;             // [64]
        float* sc1 = sred + 192;             // [64]
        int jj = t & 63, ck = t >> 6;        // ck in {0,1}
        const float* Wc = W1 + jj;
        float tp = 0.f;
        int p0 = ck * 256;
        for (int p = p0; p < p0 + 256; p += 4) {
            float4 tv = *(const float4*)(target + p);
            tp += tv.x * Wc[(size_t)(p + 0) * 64] + tv.y * Wc[(size_t)(p + 1) * 64]
                + tv.z * Wc[(size_t)(p + 2) * 64] + tv.w * Wc[(size_t)(p + 3) * 64];
        }
        spart[ck * 64 + jj] = tp;
        __syncthreads();
        if (ck == 0) {
            float c = b1[jj] + spart[jj] + spart[64 + jj];
            float c0 = c, c1 = c;
            for (int q = 0; q < 16; q++) {
                float wq = Wc[(size_t)(2 * PD + q) * 64];
                c0 += lemb[q] * wq;
                c1 += lemb[16 + q] * wq;
            }
            sc0[jj] = c0; sc1[jj] = c1;
        }
        __syncthreads();
        int wave = ck, lane = jj;
        int rr = a * 2 + wave;
        if (rr >= nseg) return;
        bool rl = rr >= N;
        const float* z = rl ? roleF + (size_t)(rr - N) * PD : formF + (size_t)rr * PD;
        const float* Wz = W1 + (size_t)PD * 64 + lane;
        float hA = rl ? sc1[lane] : sc0[lane];
        float hB = 0.f, hC = 0.f, hD = 0.f;
        for (int p = 0; p < PD; p += 8) {     // 4 independent FMA chains
            float4 z0 = *(const float4*)(z + p);
            float4 z1 = *(const float4*)(z + p + 4);
            hA += z0.x * Wz[(size_t)(p + 0) * 64] + z0.y * Wz[(size_t)(p + 1) * 64];
            hB += z0.z * Wz[(size_t)(p + 2) * 64] + z0.w * Wz[(size_t)(p + 3) * 64];
            hC += z1.x * Wz[(size_t)(p + 4) * 64] + z1.y * Wz[(size_t)(p + 5) * 64];
            hD += z1.z * Wz[(size_t)(p + 6) * 64] + z1.w * Wz[(size_t)(p + 7) * 64];
        }
        float hh = (hA + hB) + (hC + hD);
        hh = hh > 0.f ? hh : 0.2f * hh;       // LeakyReLU(0.2)
        float vv = hh * W2[lane];
#pragma unroll
        for (int off = 32; off > 0; off >>= 1) vv += __shfl_down(vv, off, 64);
        if (lane == 0) logits[rr] = vv + b2[0];
        return;
    }
    // ---- accum: sum_k w_k * drug[j_k] for segment b; 16 rows in flight ----
    int n = cnt[b]; n = n < CAP ? n : CAP;
    const int2* bb = bins + (size_t)b * CAP;
    float4 acc = make_float4(0.f, 0.f, 0.f, 0.f);
    int k = 0;
    for (; k + 15 < n; k += 16) {
        i4v q0 = __builtin_nontemporal_load(reinterpret_cast<const i4v*>(bb + k + 0));
        i4v q1 = __builtin_nontemporal_load(reinterpret_cast<const i4v*>(bb + k + 2));
        i4v q2 = __builtin_nontemporal_load(reinterpret_cast<const i4v*>(bb + k + 4));
        i4v q3 = __builtin_nontemporal_load(reinterpret_cast<const i4v*>(bb + k + 6));
        i4v q4 = __builtin_nontemporal_load(reinterpret_cast<const i4v*>(bb + k + 8));
        i4v q5 = __builtin_nontemporal_load(reinterpret_cast<const i4v*>(bb + k + 10));
        i4v q6 = __builtin_nontemporal_load(reinterpret_cast<const i4v*>(bb + k + 12));
        i4v q7 = __builtin_nontemporal_load(reinterpret_cast<const i4v*>(bb + k + 14));
        float4 d0 = ((const float4*)(drug + (size_t)q0.x * PD))[t];
        float4 d1 = ((const float4*)(drug + (size_t)q0.z * PD))[t];
        float4 d2 = ((const float4*)(drug + (size_t)q1.x * PD))[t];
        float4 d3 = ((const float4*)(drug + (size_t)q1.z * PD))[t];
        float4 d4 = ((const float4*)(drug + (size_t)q2.x * PD))[t];
        float4 d5 = ((const float4*)(drug + (size_t)q2.z * PD))[t];
        float4 d6 = ((const float4*)(drug + (size_t)q3.x * PD))[t];
        float4 d7 = ((const float4*)(drug + (size_t)q3.z * PD))[t];
        float4 d8 = ((const float4*)(drug + (size_t)q4.x * PD))[t];
        float4 d9 = ((const float4*)(drug + (size_t)q4.z * PD))[t];
        float4 da = ((const float4*)(drug + (size_t)q5.x * PD))[t];
        float4 db = ((const float4*)(drug + (size_t)q5.z * PD))[t];
        float4 dc = ((const float4*)(drug + (size_t)q6.x * PD))[t];
        float4 dd = ((const float4*)(drug + (size_t)q6.z * PD))[t];
        float4 de = ((const float4*)(drug + (size_t)q7.x * PD))[t];
        float4 df = ((const float4*)(drug + (size_t)q7.z * PD))[t];
        float w0 = __int_as_float(q0.y), w1 = __int_as_float(q0.w);
        float w2 = __int_as_float(q1.y), w3 = __int_as_float(q1.w);
        float w4 = __int_as_float(q2.y), w5 = __int_as_float(q2.w);
        float w6 = __int_as_float(q3.y), w7 = __int_as_float(q3.w);
        float w8 = __int_as_float(q4.y), w9 = __int_as_float(q4.w);
        float wa = __int_as_float(q5.y), wb = __int_as_float(q5.w);
        float wc = __int_as_float(q6.y), wd = __int_as_float(q6.w);
        float we = __int_as_float(q7.y), wf = __int_as_float(q7.w);
        acc.x += w0 * d0.x; acc.y += w0 * d0.y; acc.z += w0 * d0.z; acc.w += w0 * d0.w;
        acc.x += w1 * d1.x; acc.y += w1 * d1.y; acc.z += w1 * d1.z; acc.w += w1 * d1.w;
        acc.x += w2 * d2.x; acc.y += w2 * d2.y; acc.z += w2 * d2.z; acc.w += w2 * d2.w;
        acc.x += w3 * d3.x; acc.y += w3 * d3.y; acc.z += w3 * d3.z; acc.w += w3 * d3.w;
        acc.x += w4 * d4.x; acc.y += w4 * d4.y; acc.z += w4 * d4.z; acc.w += w4 * d4.w;
        acc.x += w5 * d5.x; acc.y += w5 * d5.y; acc.z += w5 * d5.z; acc.w += w5 * d5.w;
        acc.x += w6 * d6.x; acc.y += w6 * d6.y; acc.z += w6 * d6.z; acc.w += w6 * d6.w;
        acc.x += w7 * d7.x; acc.y += w7 * d7.y; acc.z += w7 * d7.z; acc.w += w7 * d7.w;
        acc.x += w8 * d8.x; acc.y += w8 * d8.y; acc.z += w8 * d8.z; acc.w += w8 * d8.w;
        acc.x += w9 * d9.x; acc.y += w9 * d9.y; acc.z += w9 * d9.z; acc.w += w9 * d9.w;
        acc.x += wa * da.x; acc.y += wa * da.y; acc.z += wa * da.z; acc.w += wa * da.w;
        acc.x += wb * db.x; acc.y += wb * db.y; acc.z += wb * db.z; acc.w += wb * db.w;
        acc.x += wc * dc.x; acc.y += wc * dc.y; acc.z += wc * dc.z; acc.w += wc * dc.w;
        acc.x += wd * dd.x; acc.y += wd * dd.y; acc.z += wd * dd.z; acc.w += wd * dd.w;
        acc.x += we * de.x; acc.y += we * de.y; acc.z += we * de.z; acc.w += we * de.w;
        acc.x += wf * df.x; acc.y += wf * df.y; acc.z += wf * df.z; acc.w += wf * df.w;
    }
    for (; k + 3 < n; k += 4) {
        i4v q0 = __builtin_nontemporal_load(reinterpret_cast<const i4v*>(bb + k + 0));
        i4v q1 = __builtin_nontemporal_load(reinterpret_cast<const i4v*>(bb + k + 2));
        float4 d0 = ((const float4*)(drug + (size_t)q0.x * PD))[t];
        float4 d1 = ((const float4*)(drug + (size_t)q0.z * PD))[t];
        float4 d2 = ((const float4*)(drug + (size_t)q1.x * PD))[t];
        float4 d3 = ((const float4*)(drug + (size_t)q1.z * PD))[t];
        float w0 = __int_as_float(q0.y), w1 = __int_as_float(q0.w);
        float w2 = __int_as_float(q1.y), w3 = __int_as_float(q1.w);
        acc.x += w0 * d0.x; acc.y += w0 * d0.y; acc.z += w0 * d0.z; acc.w += w0 * d0.w;
        acc.x += w1 * d1.x; acc.y += w1 * d1.y; acc.z += w1 * d1.z; acc.w += w1 * d1.w;
        acc.x += w2 * d2.x; acc.y += w2 * d2.y; acc.z += w2 * d2.z; acc.w += w2 * d2.w;
        acc.x += w3 * d3.x; acc.y += w3 * d3.y; acc.z += w3 * d3.z; acc.w += w3 * d3.w;
    }
    for (; k < n; k++) {
        int2 e0 = bb[k];
        float w0 = __int_as_float(e0.y);
        float4 d0 = ((const float4*)(drug + (size_t)e0.x * PD))[t];
        acc.x += w0 * d0.x; acc.y += w0 * d0.y; acc.z += w0 * d0.z; acc.w += w0 * d0.w;
    }
    f4v av; av.x = acc.x; av.y = acc.y; av.z = acc.z; av.w = acc.w;
    __builtin_nontemporal_store(av, reinterpret_cast<f4v*>(msgs + (size_t)b * PD) + t);
}

// ---------------------------------------------------------------------------
// Softmax stats (redundant per block -- 2x4000 extra L2 loads, negligible)
// + weighted row sum -> v_prior.
// ---------------------------------------------------------------------------
__global__ __launch_bounds__(128) void vprior_kernel(const float* __restrict__ logits,
                                                     const float* __restrict__ msgs,
                                                     int nseg, float* __restrict__ v_prior) {
    __shared__ float red[128];
    int t = threadIdx.x;
    float m = -1e30f;
    for (int s = t; s < nseg; s += 128) m = fmaxf(m, logits[s]);
    red[t] = m; __syncthreads();
    for (int o = 64; o > 0; o >>= 1) { if (t < o) red[t] = fmaxf(red[t], red[t + o]); __syncthreads(); }
    m = red[0]; __syncthreads();
    float sum = 0.f;
    for (int s = t; s < nseg; s += 128) sum += expf(logits[s] - m);
    red[t] = sum; __syncthreads();
    for (int o = 64; o > 0; o >>= 1) { if (t < o) red[t] += red[t + o]; __syncthreads(); }
    float inv = 1.f / red[0];

    float4 acc = make_float4(0.f, 0.f, 0.f, 0.f);
    for (int s = blockIdx.x; s < nseg; s += gridDim.x) {
        float w = expf(logits[s] - m) * inv;
        float4 d = ((const float4*)(msgs + (size_t)s * PD))[t];
        acc.x += w * d.x; acc.y += w * d.y; acc.z += w * d.z; acc.w += w * d.w;
    }
    atomicAdd(&v_prior[4 * t + 0], acc.x);
    atomicAdd(&v_prior[4 * t + 1], acc.y);
    atomicAdd(&v_prior[4 * t + 2], acc.z);
    atomicAdd(&v_prior[4 * t + 3], acc.w);
}

// ---------------------------------------------------------------------------
// h = v_prior @ Wi1 (partial over d-rows, atomic accumulate; bias+PReLU later)
// ---------------------------------------------------------------------------
__global__ __launch_bounds__(256) void mv1_kernel(const float* __restrict__ v_prior,
                                                  const float* __restrict__ Wi1,
                                                  float* __restrict__ h) {
    int b = blockIdx.x;    // 32 blocks x 16 rows
    int t = threadIdx.x;   // cols 2t, 2t+1
    float2 acc = make_float2(0.f, 0.f);
    int d0 = b * 16;
    for (int d = d0; d < d0 + 16; d++) {
        float vd = v_prior[d];
        float2 w = ((const float2*)(Wi1 + (size_t)d * PD))[t];
        acc.x += vd * w.x; acc.y += vd * w.y;
    }
    atomicAdd(&h[2 * t + 0], acc.x);
    atomicAdd(&h[2 * t + 1], acc.y);
}

// v = PReLU(h + bi1) @ Wi2 (partial over q-rows, atomic accumulate)
__global__ __launch_bounds__(256) void mv2_kernel(const float* __restrict__ h,
                                                  const float* __restrict__ bi1,
                                                  const float* __restrict__ alpha_p,
                                                  const float* __restrict__ Wi2,
                                                  float* __restrict__ v) {
    int b = blockIdx.x;
    int t = threadIdx.x;
    float alpha = alpha_p[0];
    float2 acc = make_float2(0.f, 0.f);
    int q0 = b * 16;
    for (int q = q0; q < q0 + 16; q++) {
        float hq = h[q] + bi1[q];
        hq = hq > 0.f ? hq : alpha * hq;
        float2 w = ((const float2*)(Wi2 + (size_t)q * PD))[t];
        acc.x += hq * w.x; acc.y += hq * w.y;
    }
    atomicAdd(&v[2 * t + 0], acc.x);
    atomicAdd(&v[2 * t + 1], acc.y);
}

// x = target + (v + bi2); LayerNorm -> z_refined (d_out[0:512])
__global__ __launch_bounds__(512) void final_kernel(const float* __restrict__ target,
                                                    const float* __restrict__ v,
                                                    const float* __restrict__ bi2,
                                                    const float* __restrict__ gamma,
                                                    const float* __restrict__ beta,
                                                    float* __restrict__ out) {
    __shared__ float red[512];
    int t = threadIdx.x;
    float x = target[t] + v[t] + bi2[t];
    red[t] = x; __syncthreads();
    for (int o = 256; o > 0; o >>= 1) { if (t < o) red[t] += red[t + o]; __syncthreads(); }
    float mu = red[0] * (1.f / 512.f);
    __syncthreads();
    float dx = x - mu;
    red[t] = dx * dx; __syncthreads();
    for (int o = 256; o > 0; o >>= 1) { if (t < o) red[t] += red[t + o]; __syncthreads(); }
    float var = red[0] * (1.f / 512.f);
    out[t] = dx * (1.f / sqrtf(var + 1e-5f)) * gamma[t] + beta[t];
}

// ---------------------------------------------------------------------------
extern "C" void kernel_launch(void* const* d_in, const int* in_sizes, int n_in,
                              void* d_out, int out_size, void* d_ws, size_t ws_size,
                              hipStream_t stream) {
    const float* target = (const float*)d_in[0];
    const float* formF  = (const float*)d_in[1];
    const float* roleF  = (const float*)d_in[2];
    const int*   nb_f   = (const int*)d_in[3];
    const int*   nb_r   = (const int*)d_in[4];
    const int*   ei_f   = (const int*)d_in[5];   // (2,E) flat: row0 src, row1 drug
    const float* y_f    = (const float*)d_in[6];
    const int*   ei_r   = (const int*)d_in[7];
    const float* y_r    = (const float*)d_in[8];
    const float* drug   = (const float*)d_in[9];
    const float* lemb   = (const float*)d_in[10];
    const float* W1     = (const float*)d_in[11];
    const float* b1     = (const float*)d_in[12];
    const float* W2     = (const float*)d_in[13];
    const float* b2     = (const float*)d_in[14];
    const float* Wi1    = (const float*)d_in[15];
    const float* bi1    = (const float*)d_in[16];
    const float* alpha  = (const float*)d_in[17];
    const float* Wi2    = (const float*)d_in[18];
    const float* bi2    = (const float*)d_in[19];
    const float* gamma  = (const float*)d_in[20];
    const float* beta   = (const float*)d_in[21];

    int N = in_sizes[3];
    int E = in_sizes[5] / 2;
    int nseg = 2 * N;

    // workspace layout (4-byte words)
    int* ws = (int*)d_ws;
    int*   cnt     = ws + 0;                 // 4096  (zeroed)
    float* v_prior = (float*)(ws + 4096);    // 512   (zeroed)
    float* hbuf    = (float*)(ws + 4608);    // 512   (zeroed)
    float* vbuf    = (float*)(ws + 5120);    // 512   (zeroed)
    float* logits  = (float*)(ws + 5632);    // 4096
    int2*  bins    = (int2*)(ws + 9728);     // word 9728 -> byte 38912, 8B aligned

    float* out  = (float*)d_out;
    float* msgs = out + PD;   // [2N, 512] = form_msgs then role_msgs

    hipMemsetAsync(ws, 0, 5632 * sizeof(int), stream);  // cnt + v_prior + h + v

    int EBf = (E + 1023) / 1024;             // edge blocks per layer (4 edges/thread)
    int AB2 = (nseg + 1) / 2;                // attention blocks: 2 waves x 1 row
    edge_kernel<<<2 * EBf, 256, 0, stream>>>(ei_f, y_f, ei_r, y_r, nb_f, nb_r,
                                             N, E, EBf, cnt, bins);
    accum_attn_kernel<<<nseg + AB2, 128, 0, stream>>>(cnt, bins, drug,
                                                      target, formF, roleF, lemb,
                                                      W1, b1, W2, b2,
                                                      nseg, logits, msgs);
    vprior_kernel<<<256, 128, 0, stream>>>(logits, msgs, nseg, v_prior);
    mv1_kernel<<<32, 256, 0, stream>>>(v_prior, Wi1, hbuf);
    mv2_kernel<<<32, 256, 0, stream>>>(hbuf, bi1, alpha, Wi2, vbuf);
    final_kernel<<<1, 512, 0, stream>>>(target, vbuf, bi2, gamma, beta, out);
}

// Round 10
// 441.309 us; speedup vs baseline: 1.0866x; 1.0786x over previous
//
#include <hip/hip_runtime.h>
#include <math.h>

// Problem constants (P == D == 512).
static constexpr int PD = 512;
static constexpr float BASEV = 6.0f;
static constexpr int CAP = 320;   // slots per segment; counts ~150 +/- 12 => +14 sigma safe

typedef float f4v __attribute__((ext_vector_type(4)));
typedef int   i4v __attribute__((ext_vector_type(4)));
typedef int   i2v __attribute__((ext_vector_type(2)));

// ---------------------------------------------------------------------------
// Front kernel: fuses (a) attention logits and (b) edge binning.
// This pairing is the measured-best overlap: edge is atomic/latency-bound
// with near-zero L2 bandwidth demand, so attention's W1 re-reads get the L2
// to themselves (R9 showed attention||accum regresses 33 us from L2 contention).
// Edge fast path: for sorted unique neighbor ids, guess g = clamp(v - nb[0]);
// if nb[g]==v and (g==0 || nb[g-1]<v), g IS searchsorted-left(v) -- O(1).
// Binary-search fallback keeps generality.
// ---------------------------------------------------------------------------
__global__ __launch_bounds__(256) void front_kernel(
    const int* __restrict__ ei_f, const float* __restrict__ y_f,
    const int* __restrict__ ei_r, const float* __restrict__ y_r,
    const int* __restrict__ nb_f, const int* __restrict__ nb_r,
    const float* __restrict__ target, const float* __restrict__ formF,
    const float* __restrict__ roleF, const float* __restrict__ lemb,
    const float* __restrict__ W1, const float* __restrict__ b1,
    const float* __restrict__ W2, const float* __restrict__ b2,
    int N, int E, int AB, int EBf,
    int* __restrict__ cnt, int2* __restrict__ bins,
    float* __restrict__ logits) {
    __shared__ float sred[384];
    int b = blockIdx.x;
    if (b >= AB) {
        // ---- edge binning: 1024 edges per block, 4 per thread ----
        int b2 = b - AB;
        bool role = b2 >= EBf;
        const int* nb = role ? nb_r : nb_f;
        const int* ei = role ? ei_r : ei_f;
        const float* yy = role ? y_r : y_f;
        int base = (role ? b2 - EBf : b2) * 1024;
        int nb0 = nb[0];
#pragma unroll
        for (int r = 0; r < 4; r++) {
            int e = base + threadIdx.x + r * 256;
            if (e >= E) continue;
            int v = ei[e];
            int g = v - nb0; g = g < 0 ? 0 : (g >= N ? N - 1 : g);
            int pos;
            if (nb[g] == v && (g == 0 || nb[g - 1] < v)) {
                pos = g;                           // O(1) hit (shifted-identity table)
            } else {
                int lo = 0, hi = N;                // general fallback
                while (lo < hi) { int mid = (lo + hi) >> 1; if (nb[mid] < v) lo = mid + 1; else hi = mid; }
                pos = lo < N ? lo : N - 1;         // clip(ss, 0, N-1)
                if (nb[pos] != v) continue;        // invalid edge -> weight 0
            }
            int s = role ? N + pos : pos;
            float w = yy[e] - BASEV;
            int slot = atomicAdd(&cnt[s], 1);
            if (slot < CAP) {
                i2v val; val.x = ei[E + e]; val.y = __float_as_int(w);
                // NT: bins are streamed once downstream; keep them out of L2
                __builtin_nontemporal_store(val, reinterpret_cast<i2v*>(bins + (size_t)s * CAP + slot));
            }
        }
    } else {
        // ---- attention ----
        // Phase 1: block-wide constant term c_l[j] = b1[j] + target.W1 + lemb_l.W1
        float* spart = sred;                 // [4][64]
        float* sc0 = spart + 256;            // [64]
        float* sc1 = spart + 320;            // [64]
        int jj = threadIdx.x & 63, ck = threadIdx.x >> 6;
        const float* Wc = W1 + jj;
        float tp = 0.f;
        int p0 = ck * 128;
        for (int p = p0; p < p0 + 128; p += 4) {
            float4 tv = *(const float4*)(target + p);
            tp += tv.x * Wc[(size_t)(p + 0) * 64] + tv.y * Wc[(size_t)(p + 1) * 64]
                + tv.z * Wc[(size_t)(p + 2) * 64] + tv.w * Wc[(size_t)(p + 3) * 64];
        }
        spart[ck * 64 + jj] = tp;
        __syncthreads();
        if (ck == 0) {
            float c = b1[jj] + spart[jj] + spart[64 + jj] + spart[128 + jj] + spart[192 + jj];
            float c0 = c, c1 = c;
            for (int q = 0; q < 16; q++) {
                float wq = Wc[(size_t)(2 * PD + q) * 64];
                c0 += lemb[q] * wq;
                c1 += lemb[16 + q] * wq;
            }
            sc0[jj] = c0; sc1[jj] = c1;
        }
        __syncthreads();
        // Phase 2: one row per wave (4 rows/block).
        int wave = threadIdx.x >> 6, lane = threadIdx.x & 63;
        int rr = b * 4 + wave;
        int nseg = 2 * N;
        if (rr >= nseg) return;
        bool rl = rr >= N;
        const float* z = rl ? roleF + (size_t)(rr - N) * PD : formF + (size_t)rr * PD;
        const float* Wz = W1 + (size_t)PD * 64 + lane;
        float hA = rl ? sc1[lane] : sc0[lane];
        float hB = 0.f, hC = 0.f, hD = 0.f;
        for (int p = 0; p < PD; p += 8) {     // 4 independent FMA chains
            float4 z0 = *(const float4*)(z + p);
            float4 z1 = *(const float4*)(z + p + 4);
            hA += z0.x * Wz[(size_t)(p + 0) * 64] + z0.y * Wz[(size_t)(p + 1) * 64];
            hB += z0.z * Wz[(size_t)(p + 2) * 64] + z0.w * Wz[(size_t)(p + 3) * 64];
            hC += z1.x * Wz[(size_t)(p + 4) * 64] + z1.y * Wz[(size_t)(p + 5) * 64];
            hD += z1.z * Wz[(size_t)(p + 6) * 64] + z1.w * Wz[(size_t)(p + 7) * 64];
        }
        float hh = (hA + hB) + (hC + hD);
        hh = hh > 0.f ? hh : 0.2f * hh;       // LeakyReLU(0.2)
        float vv = hh * W2[lane];
#pragma unroll
        for (int off = 32; off > 0; off >>= 1) vv += __shfl_down(vv, off, 64);
        if (lane == 0) logits[rr] = vv + b2[0];
    }
}

// ---------------------------------------------------------------------------
// Accumulate sum_k w_k * drug[j_k] per segment. One block (128 thr) per
// segment; float4 per thread covers 512 cols; 16 independent row loads in
// flight. NT bins loads + NT msgs stores keep the drug table hot in L2.
// Extra block (b == nseg) computes global softmax stats (m, Z) into sm[].
// ---------------------------------------------------------------------------
__global__ __launch_bounds__(128) void accum_kernel(const int* __restrict__ cnt,
                                                    const int2* __restrict__ bins,
                                                    const float* __restrict__ drug,
                                                    const float* __restrict__ logits,
                                                    int nseg,
                                                    float* __restrict__ sm,
                                                    float* __restrict__ msgs) {
    int b = blockIdx.x;
    int t = threadIdx.x;
    if (b == nseg) {
        // softmax stats over logits[0..nseg)
        __shared__ float red[128];
        float m = -1e30f;
        for (int s = t; s < nseg; s += 128) m = fmaxf(m, logits[s]);
        red[t] = m; __syncthreads();
        for (int o = 64; o > 0; o >>= 1) { if (t < o) red[t] = fmaxf(red[t], red[t + o]); __syncthreads(); }
        m = red[0]; __syncthreads();
        float sum = 0.f;
        for (int s = t; s < nseg; s += 128) sum += expf(logits[s] - m);
        red[t] = sum; __syncthreads();
        for (int o = 64; o > 0; o >>= 1) { if (t < o) red[t] += red[t + o]; __syncthreads(); }
        if (t == 0) { sm[0] = m; sm[1] = red[0]; }
        return;
    }
    int n = cnt[b]; n = n < CAP ? n : CAP;
    const int2* bb = bins + (size_t)b * CAP;
    float4 acc = make_float4(0.f, 0.f, 0.f, 0.f);
    int k = 0;
    for (; k + 15 < n; k += 16) {
        i4v q0 = __builtin_nontemporal_load(reinterpret_cast<const i4v*>(bb + k + 0));
        i4v q1 = __builtin_nontemporal_load(reinterpret_cast<const i4v*>(bb + k + 2));
        i4v q2 = __builtin_nontemporal_load(reinterpret_cast<const i4v*>(bb + k + 4));
        i4v q3 = __builtin_nontemporal_load(reinterpret_cast<const i4v*>(bb + k + 6));
        i4v q4 = __builtin_nontemporal_load(reinterpret_cast<const i4v*>(bb + k + 8));
        i4v q5 = __builtin_nontemporal_load(reinterpret_cast<const i4v*>(bb + k + 10));
        i4v q6 = __builtin_nontemporal_load(reinterpret_cast<const i4v*>(bb + k + 12));
        i4v q7 = __builtin_nontemporal_load(reinterpret_cast<const i4v*>(bb + k + 14));
        float4 d0 = ((const float4*)(drug + (size_t)q0.x * PD))[t];
        float4 d1 = ((const float4*)(drug + (size_t)q0.z * PD))[t];
        float4 d2 = ((const float4*)(drug + (size_t)q1.x * PD))[t];
        float4 d3 = ((const float4*)(drug + (size_t)q1.z * PD))[t];
        float4 d4 = ((const float4*)(drug + (size_t)q2.x * PD))[t];
        float4 d5 = ((const float4*)(drug + (size_t)q2.z * PD))[t];
        float4 d6 = ((const float4*)(drug + (size_t)q3.x * PD))[t];
        float4 d7 = ((const float4*)(drug + (size_t)q3.z * PD))[t];
        float4 d8 = ((const float4*)(drug + (size_t)q4.x * PD))[t];
        float4 d9 = ((const float4*)(drug + (size_t)q4.z * PD))[t];
        float4 da = ((const float4*)(drug + (size_t)q5.x * PD))[t];
        float4 db = ((const float4*)(drug + (size_t)q5.z * PD))[t];
        float4 dc = ((const float4*)(drug + (size_t)q6.x * PD))[t];
        float4 dd = ((const float4*)(drug + (size_t)q6.z * PD))[t];
        float4 de = ((const float4*)(drug + (size_t)q7.x * PD))[t];
        float4 df = ((const float4*)(drug + (size_t)q7.z * PD))[t];
        float w0 = __int_as_float(q0.y), w1 = __int_as_float(q0.w);
        float w2 = __int_as_float(q1.y), w3 = __int_as_float(q1.w);
        float w4 = __int_as_float(q2.y), w5 = __int_as_float(q2.w);
        float w6 = __int_as_float(q3.y), w7 = __int_as_float(q3.w);
        float w8 = __int_as_float(q4.y), w9 = __int_as_float(q4.w);
        float wa = __int_as_float(q5.y), wb = __int_as_float(q5.w);
        float wc = __int_as_float(q6.y), wd = __int_as_float(q6.w);
        float we = __int_as_float(q7.y), wf = __int_as_float(q7.w);
        acc.x += w0 * d0.x; acc.y += w0 * d0.y; acc.z += w0 * d0.z; acc.w += w0 * d0.w;
        acc.x += w1 * d1.x; acc.y += w1 * d1.y; acc.z += w1 * d1.z; acc.w += w1 * d1.w;
        acc.x += w2 * d2.x; acc.y += w2 * d2.y; acc.z += w2 * d2.z; acc.w += w2 * d2.w;
        acc.x += w3 * d3.x; acc.y += w3 * d3.y; acc.z += w3 * d3.z; acc.w += w3 * d3.w;
        acc.x += w4 * d4.x; acc.y += w4 * d4.y; acc.z += w4 * d4.z; acc.w += w4 * d4.w;
        acc.x += w5 * d5.x; acc.y += w5 * d5.y; acc.z += w5 * d5.z; acc.w += w5 * d5.w;
        acc.x += w6 * d6.x; acc.y += w6 * d6.y; acc.z += w6 * d6.z; acc.w += w6 * d6.w;
        acc.x += w7 * d7.x; acc.y += w7 * d7.y; acc.z += w7 * d7.z; acc.w += w7 * d7.w;
        acc.x += w8 * d8.x; acc.y += w8 * d8.y; acc.z += w8 * d8.z; acc.w += w8 * d8.w;
        acc.x += w9 * d9.x; acc.y += w9 * d9.y; acc.z += w9 * d9.z; acc.w += w9 * d9.w;
        acc.x += wa * da.x; acc.y += wa * da.y; acc.z += wa * da.z; acc.w += wa * da.w;
        acc.x += wb * db.x; acc.y += wb * db.y; acc.z += wb * db.z; acc.w += wb * db.w;
        acc.x += wc * dc.x; acc.y += wc * dc.y; acc.z += wc * dc.z; acc.w += wc * dc.w;
        acc.x += wd * dd.x; acc.y += wd * dd.y; acc.z += wd * dd.z; acc.w += wd * dd.w;
        acc.x += we * de.x; acc.y += we * de.y; acc.z += we * de.z; acc.w += we * de.w;
        acc.x += wf * df.x; acc.y += wf * df.y; acc.z += wf * df.z; acc.w += wf * df.w;
    }
    for (; k + 3 < n; k += 4) {
        i4v q0 = __builtin_nontemporal_load(reinterpret_cast<const i4v*>(bb + k + 0));
        i4v q1 = __builtin_nontemporal_load(reinterpret_cast<const i4v*>(bb + k + 2));
        float4 d0 = ((const float4*)(drug + (size_t)q0.x * PD))[t];
        float4 d1 = ((const float4*)(drug + (size_t)q0.z * PD))[t];
        float4 d2 = ((const float4*)(drug + (size_t)q1.x * PD))[t];
        float4 d3 = ((const float4*)(drug + (size_t)q1.z * PD))[t];
        float w0 = __int_as_float(q0.y), w1 = __int_as_float(q0.w);
        float w2 = __int_as_float(q1.y), w3 = __int_as_float(q1.w);
        acc.x += w0 * d0.x; acc.y += w0 * d0.y; acc.z += w0 * d0.z; acc.w += w0 * d0.w;
        acc.x += w1 * d1.x; acc.y += w1 * d1.y; acc.z += w1 * d1.z; acc.w += w1 * d1.w;
        acc.x += w2 * d2.x; acc.y += w2 * d2.y; acc.z += w2 * d2.z; acc.w += w2 * d2.w;
        acc.x += w3 * d3.x; acc.y += w3 * d3.y; acc.z += w3 * d3.z; acc.w += w3 * d3.w;
    }
    for (; k < n; k++) {
        int2 e0 = bb[k];
        float w0 = __int_as_float(e0.y);
        float4 d0 = ((const float4*)(drug + (size_t)e0.x * PD))[t];
        acc.x += w0 * d0.x; acc.y += w0 * d0.y; acc.z += w0 * d0.z; acc.w += w0 * d0.w;
    }
    f4v av; av.x = acc.x; av.y = acc.y; av.z = acc.z; av.w = acc.w;
    __builtin_nontemporal_store(av, reinterpret_cast<f4v*>(msgs + (size_t)b * PD) + t);
}

// ---------------------------------------------------------------------------
// Weighted row sum -> v_prior, using precomputed softmax stats sm = {m, Z}.
// ---------------------------------------------------------------------------
__global__ __launch_bounds__(128) void vprior_kernel(const float* __restrict__ logits,
                                                     const float* __restrict__ msgs,
                                                     const float* __restrict__ sm,
                                                     int nseg, float* __restrict__ v_prior) {
    int t = threadIdx.x;
    float m = sm[0];
    float inv = 1.f / sm[1];
    float4 acc = make_float4(0.f, 0.f, 0.f, 0.f);
    for (int s = blockIdx.x; s < nseg; s += gridDim.x) {
        float w = expf(logits[s] - m) * inv;
        float4 d = ((const float4*)(msgs + (size_t)s * PD))[t];
        acc.x += w * d.x; acc.y += w * d.y; acc.z += w * d.z; acc.w += w * d.w;
    }
    atomicAdd(&v_prior[4 * t + 0], acc.x);
    atomicAdd(&v_prior[4 * t + 1], acc.y);
    atomicAdd(&v_prior[4 * t + 2], acc.z);
    atomicAdd(&v_prior[4 * t + 3], acc.w);
}

// ---------------------------------------------------------------------------
// h = v_prior @ Wi1 (partial over d-rows, atomic accumulate; bias+PReLU later)
// ---------------------------------------------------------------------------
__global__ __launch_bounds__(256) void mv1_kernel(const float* __restrict__ v_prior,
                                                  const float* __restrict__ Wi1,
                                                  float* __restrict__ h) {
    int b = blockIdx.x;    // 32 blocks x 16 rows
    int t = threadIdx.x;   // cols 2t, 2t+1
    float2 acc = make_float2(0.f, 0.f);
    int d0 = b * 16;
    for (int d = d0; d < d0 + 16; d++) {
        float vd = v_prior[d];
        float2 w = ((const float2*)(Wi1 + (size_t)d * PD))[t];
        acc.x += vd * w.x; acc.y += vd * w.y;
    }
    atomicAdd(&h[2 * t + 0], acc.x);
    atomicAdd(&h[2 * t + 1], acc.y);
}

// v = PReLU(h + bi1) @ Wi2 (partial over q-rows, atomic accumulate)
__global__ __launch_bounds__(256) void mv2_kernel(const float* __restrict__ h,
                                                  const float* __restrict__ bi1,
                                                  const float* __restrict__ alpha_p,
                                                  const float* __restrict__ Wi2,
                                                  float* __restrict__ v) {
    int b = blockIdx.x;
    int t = threadIdx.x;
    float alpha = alpha_p[0];
    float2 acc = make_float2(0.f, 0.f);
    int q0 = b * 16;
    for (int q = q0; q < q0 + 16; q++) {
        float hq = h[q] + bi1[q];
        hq = hq > 0.f ? hq : alpha * hq;
        float2 w = ((const float2*)(Wi2 + (size_t)q * PD))[t];
        acc.x += hq * w.x; acc.y += hq * w.y;
    }
    atomicAdd(&v[2 * t + 0], acc.x);
    atomicAdd(&v[2 * t + 1], acc.y);
}

// x = target + (v + bi2); LayerNorm -> z_refined (d_out[0:512])
__global__ __launch_bounds__(512) void final_kernel(const float* __restrict__ target,
                                                    const float* __restrict__ v,
                                                    const float* __restrict__ bi2,
                                                    const float* __restrict__ gamma,
                                                    const float* __restrict__ beta,
                                                    float* __restrict__ out) {
    __shared__ float red[512];
    int t = threadIdx.x;
    float x = target[t] + v[t] + bi2[t];
    red[t] = x; __syncthreads();
    for (int o = 256; o > 0; o >>= 1) { if (t < o) red[t] += red[t + o]; __syncthreads(); }
    float mu = red[0] * (1.f / 512.f);
    __syncthreads();
    float dx = x - mu;
    red[t] = dx * dx; __syncthreads();
    for (int o = 256; o > 0; o >>= 1) { if (t < o) red[t] += red[t + o]; __syncthreads(); }
    float var = red[0] * (1.f / 512.f);
    out[t] = dx * (1.f / sqrtf(var + 1e-5f)) * gamma[t] + beta[t];
}

// ---------------------------------------------------------------------------
extern "C" void kernel_launch(void* const* d_in, const int* in_sizes, int n_in,
                              void* d_out, int out_size, void* d_ws, size_t ws_size,
                              hipStream_t stream) {
    const float* target = (const float*)d_in[0];
    const float* formF  = (const float*)d_in[1];
    const float* roleF  = (const float*)d_in[2];
    const int*   nb_f   = (const int*)d_in[3];
    const int*   nb_r   = (const int*)d_in[4];
    const int*   ei_f   = (const int*)d_in[5];   // (2,E) flat: row0 src, row1 drug
    const float* y_f    = (const float*)d_in[6];
    const int*   ei_r   = (const int*)d_in[7];
    const float* y_r    = (const float*)d_in[8];
    const float* drug   = (const float*)d_in[9];
    const float* lemb   = (const float*)d_in[10];
    const float* W1     = (const float*)d_in[11];
    const float* b1     = (const float*)d_in[12];
    const float* W2     = (const float*)d_in[13];
    const float* b2     = (const float*)d_in[14];
    const float* Wi1    = (const float*)d_in[15];
    const float* bi1    = (const float*)d_in[16];
    const float* alpha  = (const float*)d_in[17];
    const float* Wi2    = (const float*)d_in[18];
    const float* bi2    = (const float*)d_in[19];
    const float* gamma  = (const float*)d_in[20];
    const float* beta   = (const float*)d_in[21];

    int N = in_sizes[3];
    int E = in_sizes[5] / 2;
    int nseg = 2 * N;

    // workspace layout (4-byte words)
    int* ws = (int*)d_ws;
    int*   cnt     = ws + 0;                 // 4096  (zeroed)
    float* v_prior = (float*)(ws + 4096);    // 512   (zeroed)
    float* hbuf    = (float*)(ws + 4608);    // 512   (zeroed)
    float* vbuf    = (float*)(ws + 5120);    // 512   (zeroed)
    float* logits  = (float*)(ws + 5632);    // 4096
    float* smbuf   = (float*)(ws + 9728);    // 2 (softmax stats m, Z)
    int2*  bins    = (int2*)(ws + 9736);     // 8B aligned; 4096*CAP int2

    float* out  = (float*)d_out;
    float* msgs = out + PD;   // [2N, 512] = form_msgs then role_msgs

    hipMemsetAsync(ws, 0, 5632 * sizeof(int), stream);  // cnt + v_prior + h + v

    int AB  = (nseg + 3) / 4;                // attention blocks: 4 waves x 1 row
    int EBf = (E + 1023) / 1024;             // edge blocks per layer (4 edges/thread)
    front_kernel<<<AB + 2 * EBf, 256, 0, stream>>>(ei_f, y_f, ei_r, y_r, nb_f, nb_r,
                                                   target, formF, roleF, lemb,
                                                   W1, b1, W2, b2, N, E, AB, EBf,
                                                   cnt, bins, logits);
    accum_kernel<<<nseg + 1, 128, 0, stream>>>(cnt, bins, drug, logits, nseg, smbuf, msgs);
    vprior_kernel<<<256, 128, 0, stream>>>(logits, msgs, smbuf, nseg, v_prior);
    mv1_kernel<<<32, 256, 0, stream>>>(v_prior, Wi1, hbuf);
    mv2_kernel<<<32, 256, 0, stream>>>(hbuf, bi1, alpha, Wi2, vbuf);
    final_kernel<<<1, 512, 0, stream>>>(target, vbuf, bi2, gamma, beta, out);
}